// Round 7
// baseline (378.717 us; speedup 1.0000x reference)
//
#include <hip/hip_runtime.h>
#include <math.h>

// NPTransitionPrior: B=64, T=514, D=32, H=128, LAGS=2, IN=65
// out (fp32): residuals (64*512*32) | sumlogdet (64) | hist_jac (32*32768*64)
//
// R7 = R6 with the x hi/lo split moved BACK to a one-shot split_x kernel.
//  R2 folded the split into main for ws-size safety, but that made all 32
//  d-blocks re-convert the same x tile: ~165 redundant VALU ops/thread
//  (~35-40us across the grid). To fit the proven 7,000,064 B ws bound with
//  the 5.26MB XS arrays, the 4MB d-major residual buffer is dropped:
//  residuals write directly to out (partial-line cost ~8us HBM << the
//  redundant-VALU cost) and finish_res is deleted.
//  Kept from R6: phase-2 operand swap mfma(W1T,g) with direct coalesced
//  stores (no LDS transpose), ep float4 table for epilogue scalars,
//  two-ht-pass phase 1 (32-reg accumulators).
//  ws total: XS(5,263,360) + W1F(1,048,576) + W1TF(524,288) + EP(65,536)
//          = 6,901,760 B  (< proven 7,000,064).

typedef _Float16 f16;
typedef __attribute__((ext_vector_type(8))) _Float16 half8;
typedef __attribute__((ext_vector_type(4))) _Float16 half4;
typedef __attribute__((ext_vector_type(4))) float floatx4;

namespace {
// ---- workspace layout (bytes) ----
constexpr int    XS_ROW   = 40;                                // f16 per padded x row (32+8)
constexpr size_t XS_SPLIT = (size_t)64 * 514 * XS_ROW * 2;     // 2,631,680
constexpr size_t WS_XS_HI = 0;
constexpr size_t WS_XS_LO = XS_SPLIT;                          // 2,631,680
constexpr size_t W1F_SZ   = (size_t)32 * 8192 * 2;             // 524,288 per array
constexpr size_t WS_W1F_HI = 2 * XS_SPLIT;                     // 5,263,360
constexpr size_t WS_W1F_LO = WS_W1F_HI + W1F_SZ;               // 5,787,648
constexpr size_t WS_W1TF   = WS_W1F_LO + W1F_SZ;               // 6,311,936
constexpr size_t WS_EP     = WS_W1TF + W1F_SZ;                 // 6,836,224 (+65,536 = 6,901,760)

constexpr int GB_HP  = 136;  // halves per GB row (128+8) -> odd 16B units, b128-clean

// ---- LDS layout (bytes) ----
constexpr int L_GB   = 0;                  // 64*136*2 = 17408
constexpr int L_XSHI = 17408;              // 66*40*2 = 5280
constexpr int L_XSLO = L_XSHI + 5280;      // 22688
constexpr int L_YY   = L_XSLO + 5280;      // 27968 (64 f32)
constexpr int L_RES  = L_YY + 256;         // 4*64 f32
constexpr int L_JAC  = L_RES + 1024;
constexpr int L_TOTAL = L_JAC + 1024;      // 30272 bytes -> up to 5 blocks/CU

constexpr size_t OUT1_OFF = (size_t)64 * 512 * 32;   // 1048576
constexpr size_t OUT2_OFF = OUT1_OFF + 64;
}

// ---- one-shot split of x into f16 hi + (lo*4096), padded rows of 40 ----
__global__ __launch_bounds__(256) void split_x_kernel(
    const float* __restrict__ x, f16* __restrict__ xh, f16* __restrict__ xl)
{
    int idx = blockIdx.x * 256 + threadIdx.x;
    if (idx >= 64 * 514 * 32) return;
    int row = idx >> 5, c = idx & 31;
    float v = x[idx];
    f16 hi = (f16)v;
    float r = v - (float)hi;
    xh[row * XS_ROW + c] = hi;
    xl[row * XS_ROW + c] = (f16)(r * 4096.0f);
}

// ---- split W1[:, :, :64] into FRAGMENT-LINEAR layouts + epilogue table ----
// phase-1 A frags: [d][hblk=h>>4][ks=k>>5][lane=q*16+(h&15)][j=k&7]  (hi and lo)
// phase-2 A frags: [d][ks=h>>5][kt=k>>4][lane=q2*16+(k&15)][j=h&7]   (hi only)
// ep table: [d][h] -> float4 {b1, W2, 0.01*W2, W1[..,64]}
__global__ __launch_bounds__(256) void split_w1_kernel(
    const float* __restrict__ W1, const float* __restrict__ b1,
    const float* __restrict__ W2,
    f16* __restrict__ wh, f16* __restrict__ wl,
    f16* __restrict__ wT, float4* __restrict__ ep)
{
    int idx = blockIdx.x * 256 + threadIdx.x;
    if (idx >= 32 * 128 * 64) return;
    int d = idx >> 13, rem = idx & 8191;
    int h = rem >> 6, k = rem & 63;
    float v = W1[((size_t)(d * 128 + h)) * 65 + k];
    f16 hi = (f16)v;
    float r = v - (float)hi;
    int lane1 = (((k >> 3) & 3) << 4) | (h & 15);
    size_t o1 = ((((size_t)d * 8 + (h >> 4)) * 2 + (k >> 5)) * 64 + lane1) * 8 + (k & 7);
    wh[o1] = hi;
    wl[o1] = (f16)(r * 4096.0f);
    int lane2 = (((h >> 3) & 3) << 4) | (k & 15);
    size_t o2 = ((((size_t)d * 4 + (h >> 5)) * 4 + (k >> 4)) * 64 + lane2) * 8 + (h & 7);
    wT[o2] = hi;
    if (k == 63) {
        int hh = d * 128 + h;
        float w2 = W2[hh];
        float4 e;
        e.x = b1[hh];
        e.y = w2;
        e.z = 0.01f * w2;
        e.w = W1[(size_t)hh * 65 + 64];
        ep[hh] = e;
    }
}

__global__ __launch_bounds__(256, 4) void np_main_kernel(
    const float* __restrict__ x,    // (64,514,32)
    const float* __restrict__ b2,   // (32,)
    const char* __restrict__ ws,
    float* __restrict__ out)
{
    extern __shared__ char smem[];
    const int tile = blockIdx.x;          // 0..511
    const int d    = blockIdx.y;          // 0..31
    const int b    = tile >> 3;
    const int t0   = (tile & 7) << 6;     // 64-window tile
    const int tid  = threadIdx.x;
    const int wave = tid >> 6, lane = tid & 63;
    const int c = lane & 15, q = lane >> 4;

    float* yyL  = (float*)(smem + L_YY);
    float* resP = (float*)(smem + L_RES);
    float* jacP = (float*)(smem + L_JAC);

    const f16* w1fh = (const f16*)(ws + WS_W1F_HI) + (size_t)d * 8192;
    const f16* w1fl = (const f16*)(ws + WS_W1F_LO) + (size_t)d * 8192;
    const f16* w1tf = (const f16*)(ws + WS_W1TF)   + (size_t)d * 8192;
    const float4* epd = (const float4*)(ws + WS_EP) + d * 128;

    // ---------- stage: pre-split XS tile (pure float4 copies) + yy ----------
    {
        const float4* s3 = (const float4*)(ws + WS_XS_HI + (size_t)(b * 514 + t0) * (XS_ROW * 2));
        const float4* s4 = (const float4*)(ws + WS_XS_LO + (size_t)(b * 514 + t0) * (XS_ROW * 2));
        float4* d3 = (float4*)(smem + L_XSHI);
        float4* d4 = (float4*)(smem + L_XSLO);
        for (int i = tid; i < 330; i += 256) { d3[i] = s3[i]; d4[i] = s4[i]; }
        if (tid < 64) yyL[tid] = x[(size_t)(b * 514 + t0 + tid + 2) * 32 + d];
    }
    __syncthreads();

    float yyv[4];
    #pragma unroll
    for (int nt = 0; nt < 4; ++nt) yyv[nt] = yyL[nt * 16 + c];

    float res[4] = {0.f, 0.f, 0.f, 0.f}, j64[4] = {0.f, 0.f, 0.f, 0.f};

    // ---------- phase 1 in two ht-passes: {24 MFMA -> epilogue} each ----------
    #pragma unroll
    for (int ht = 0; ht < 2; ++ht) {
        const int hbase = wave * 32 + ht * 16 + q * 4;   // D row = q*4 + reg

        // epilogue scalar table: 4 broadcast float4 loads (L1/L2-hot)
        float4 epv[4];
        #pragma unroll
        for (int r = 0; r < 4; ++r) epv[r] = epd[hbase + r];

        floatx4 accP[4], accQ[4];
        #pragma unroll
        for (int nt = 0; nt < 4; ++nt) { accP[nt] = (floatx4)0.f; accQ[nt] = (floatx4)0.f; }

        #pragma unroll
        for (int ks = 0; ks < 2; ++ks) {
            const int fo = (((wave * 2 + ht) * 2 + ks) * 64 + lane) * 8;
            const half8 aH = *(const half8*)(w1fh + fo);
            const half8 aL = *(const half8*)(w1fl + fo);
            half8 bH[4], bL[4];
            #pragma unroll
            for (int nt = 0; nt < 4; ++nt) {
                const int off = (nt * 16 + c + ks) * XS_ROW + q * 8;  // window overlap trick
                bH[nt] = *(const half8*)(smem + L_XSHI + off * 2);
                bL[nt] = *(const half8*)(smem + L_XSLO + off * 2);
            }
            #pragma unroll
            for (int nt = 0; nt < 4; ++nt) {
                accP[nt] = __builtin_amdgcn_mfma_f32_16x16x32_f16(aH, bH[nt], accP[nt], 0, 0, 0);
                accQ[nt] = __builtin_amdgcn_mfma_f32_16x16x32_f16(aH, bL[nt], accQ[nt], 0, 0, 0);
                accQ[nt] = __builtin_amdgcn_mfma_f32_16x16x32_f16(aL, bH[nt], accQ[nt], 0, 0, 0);
            }
        }

        // epilogue for this ht: pre -> g (LDS, per-wave h-columns), partials
        // (GB region disjoint from XS -> no barrier needed)
        #pragma unroll
        for (int nt = 0; nt < 4; ++nt) {
            const int n = nt * 16 + c;                   // D col = lane&15
            half4 gp;
            #pragma unroll
            for (int r = 0; r < 4; ++r) {
                const float pre = accP[nt][r] + accQ[nt][r] * (1.0f / 4096.0f)
                                + epv[r].x + yyv[nt] * epv[r].w;
                const float gg = (pre >= 0.f) ? epv[r].y : epv[r].z;
                res[nt] += pre * gg;
                j64[nt] += gg * epv[r].w;
                gp[r] = (f16)gg;
            }
            *(half4*)(smem + L_GB + (n * GB_HP + hbase) * 2) = gp;
        }
    }

    #pragma unroll
    for (int nt = 0; nt < 4; ++nt) {
        float rv = res[nt];
        rv += __shfl_xor(rv, 16, 64);
        rv += __shfl_xor(rv, 32, 64);
        float jv = j64[nt];
        jv += __shfl_xor(jv, 16, 64);
        jv += __shfl_xor(jv, 32, 64);
        if (lane < 16) {
            resP[wave * 64 + nt * 16 + lane] = rv;
            jacP[wave * 64 + nt * 16 + lane] = jv;
        }
    }
    __syncthreads();

    // ---------- residuals (direct to out) + logabsdet (one wave) ----------
    if (tid < 64) {
        const int n = tid;
        float r = b2[d], j = 0.f;
        #pragma unroll
        for (int w = 0; w < 4; ++w) { r += resP[w * 64 + n]; j += jacP[w * 64 + n]; }
        out[(size_t)(b * 512 + t0 + n) * 32 + d] = r;
        float lg = logf(fabsf(j));
        #pragma unroll
        for (int off = 32; off > 0; off >>= 1) lg += __shfl_down(lg, off, 64);
        if (tid == 0) atomicAdd(out + OUT1_OFF + b, lg);
    }

    // ---------- phase 2 (operand-swapped): jac[n,k] via mfma(W1T, g) ----------
    // A = w1tf frag (already A-layout [m=k][kk=h]); B = g from GB.
    // D: lane(c,q) reg r = jac[n=c][k=kt*16+q*4+r] -> direct dwordx4 stores,
    // lanes {c,c+16,c+32,c+48} form contiguous 64B; kt covers the 256B row.
    floatx4 acc2[4];
    #pragma unroll
    for (int kt = 0; kt < 4; ++kt) acc2[kt] = (floatx4)0.f;
    #pragma unroll
    for (int ks = 0; ks < 4; ++ks) {
        const half8 gF = *(const half8*)(smem + L_GB + ((wave * 16 + c) * GB_HP + ks * 32 + q * 8) * 2);
        #pragma unroll
        for (int kt = 0; kt < 4; ++kt) {
            const half8 wF = *(const half8*)(w1tf + ((ks * 4 + kt) * 64 + lane) * 8);
            acc2[kt] = __builtin_amdgcn_mfma_f32_16x16x32_f16(wF, gF, acc2[kt], 0, 0, 0);
        }
    }
    {
        float* out2 = out + OUT2_OFF + (size_t)d * ((size_t)32768 * 64)
                    + (size_t)(b * 512 + t0 + wave * 16) * 64;
        #pragma unroll
        for (int kt = 0; kt < 4; ++kt)
            *(floatx4*)(out2 + (size_t)c * 64 + kt * 16 + q * 4) = acc2[kt];
    }
}

extern "C" void kernel_launch(void* const* d_in, const int* in_sizes, int n_in,
                              void* d_out, int out_size, void* d_ws, size_t ws_size,
                              hipStream_t stream) {
    const float* x  = (const float*)d_in[0];
    const float* W1 = (const float*)d_in[1];
    const float* b1 = (const float*)d_in[2];
    const float* W2 = (const float*)d_in[3];
    const float* b2 = (const float*)d_in[4];
    float* out = (float*)d_out;
    char* ws = (char*)d_ws;

    hipMemsetAsync(out + OUT1_OFF, 0, 64 * sizeof(float), stream);

    hipLaunchKernelGGL(split_x_kernel, dim3((64 * 514 * 32 + 255) / 256), dim3(256), 0, stream,
                       x, (f16*)(ws + WS_XS_HI), (f16*)(ws + WS_XS_LO));
    hipLaunchKernelGGL(split_w1_kernel, dim3((32 * 128 * 64 + 255) / 256), dim3(256), 0, stream,
                       W1, b1, W2, (f16*)(ws + WS_W1F_HI), (f16*)(ws + WS_W1F_LO),
                       (f16*)(ws + WS_W1TF), (float4*)(ws + WS_EP));

    hipLaunchKernelGGL(np_main_kernel, dim3(512, 32), dim3(256), L_TOTAL, stream,
                       x, b2, (const char*)ws, out);
}

// Round 8
// 363.042 us; speedup vs baseline: 1.0432x; 1.0432x over previous
//
#include <hip/hip_runtime.h>
#include <math.h>

// NPTransitionPrior: B=64, T=514, D=32, H=128, LAGS=2, IN=65
// out (fp32): residuals (64*512*32) | sumlogdet (64) | hist_jac (32*32768*64)
//
// R8 = exact R5 (best, 362.7us) + ONE change: phase-2 kt-ownership.
//  R5 phase 2: each wave owned 16 n-rows and read the ENTIRE 16KB w1tf
//  (4x redundant per block -> 1.07 GB aggregate L2 reads). Now each wave
//  owns one 16-k slice: wF loads 16 -> 4 per wave (no redundancy, 262 MB),
//  gF LDS reads 4 -> 16 b128, and the operand-swapped MFMA (validated
//  numerically in R6: identical absmax) gives D[k][n] per lane with 4
//  consecutive k -> direct coalesced dwordx4 stores; the 16x64 LDS
//  transpose round-trip is deleted (net LDS ~flat).
//  Everything else byte-identical to R5: in-kernel x split, LDS scalar
//  tables, two-ht-pass phase 1 (32-reg acc), resw d-major + finish_res.

typedef _Float16 f16;
typedef __attribute__((ext_vector_type(8))) _Float16 half8;
typedef __attribute__((ext_vector_type(4))) _Float16 half4;
typedef __attribute__((ext_vector_type(4))) float floatx4;

namespace {
// ---- workspace layout (bytes) ----
constexpr size_t W1F_SZ    = (size_t)32 * 8192 * 2;              // 524,288 per array
constexpr size_t WS_W1F_HI = 0;
constexpr size_t WS_W1F_LO = W1F_SZ;                             // 524,288
constexpr size_t WS_W1TF   = 2 * W1F_SZ;                         // 1,048,576
constexpr size_t WS_W64    = 3 * W1F_SZ;                         // 1,572,864 (32*128 f32)
constexpr size_t WS_RES    = WS_W64 + (size_t)32 * 128 * 4;      // 1,589,248 (4 MB)
// total ws need: WS_RES + 64*512*32*4 = 5,783,552 bytes  (< proven 7,000,064)

constexpr int XS_ROW = 40;   // f16 per padded x row (32+8)
constexpr int GB_HP  = 136;  // halves per GB row (128+8) -> odd 16B units, b128-clean

// ---- LDS layout (bytes) ----
constexpr int L_GB   = 0;                  // 64*136*2 = 17408
constexpr int L_XSHI = 17408;              // 66*40*2 = 5280
constexpr int L_XSLO = L_XSHI + 5280;      // 22688
constexpr int L_B1   = L_XSLO + 5280;      // 27968 (128 f32)
constexpr int L_W2   = L_B1 + 512;
constexpr int L_W64  = L_W2 + 512;
constexpr int L_YY   = L_W64 + 512;        // 64 f32
constexpr int L_RES  = L_YY + 256;         // 4*64 f32
constexpr int L_JAC  = L_RES + 1024;
constexpr int L_TOTAL = L_JAC + 1024;      // 31808 bytes -> up to 5 blocks/CU

constexpr size_t OUT1_OFF = (size_t)64 * 512 * 32;   // 1048576
constexpr size_t OUT2_OFF = OUT1_OFF + 64;
}

// ---- split W1[:, :, :64] into FRAGMENT-LINEAR layouts ----
// phase-1 A frags: [d][hblk=h>>4][ks=k>>5][lane=q*16+(h&15)][j=k&7]  (hi and lo)
// phase-2 A frags: [d][ks=h>>5][kt=k>>4][lane=q2*16+(k&15)][j=h&7]   (hi only)
__global__ __launch_bounds__(256) void split_w1_kernel(
    const float* __restrict__ W1, f16* __restrict__ wh, f16* __restrict__ wl,
    f16* __restrict__ wT, float* __restrict__ w64)
{
    int idx = blockIdx.x * 256 + threadIdx.x;
    if (idx >= 32 * 128 * 64) return;
    int d = idx >> 13, rem = idx & 8191;
    int h = rem >> 6, k = rem & 63;
    float v = W1[((size_t)(d * 128 + h)) * 65 + k];
    f16 hi = (f16)v;
    float r = v - (float)hi;
    int lane1 = (((k >> 3) & 3) << 4) | (h & 15);
    size_t o1 = ((((size_t)d * 8 + (h >> 4)) * 2 + (k >> 5)) * 64 + lane1) * 8 + (k & 7);
    wh[o1] = hi;
    wl[o1] = (f16)(r * 4096.0f);
    int lane2 = (((h >> 3) & 3) << 4) | (k & 15);
    size_t o2 = ((((size_t)d * 4 + (h >> 5)) * 4 + (k >> 4)) * 64 + lane2) * 8 + (h & 7);
    wT[o2] = hi;
    if (k == 63) w64[d * 128 + h] = W1[((size_t)(d * 128 + h)) * 65 + 64];
}

__global__ __launch_bounds__(256, 4) void np_main_kernel(
    const float* __restrict__ x,    // (64,514,32)
    const float* __restrict__ b1,   // (32,128)
    const float* __restrict__ W2,   // (32,128)
    const float* __restrict__ b2,   // (32,)
    const char* __restrict__ ws,
    float* __restrict__ resw,       // d-major residuals (32, 32768)
    float* __restrict__ out)
{
    extern __shared__ char smem[];
    const int tile = blockIdx.x;          // 0..511
    const int d    = blockIdx.y;          // 0..31
    const int b    = tile >> 3;
    const int t0   = (tile & 7) << 6;     // 64-window tile
    const int tid  = threadIdx.x;
    const int wave = tid >> 6, lane = tid & 63;
    const int c = lane & 15, q = lane >> 4;

    float* b1L  = (float*)(smem + L_B1);
    float* W2L  = (float*)(smem + L_W2);
    float* w64L = (float*)(smem + L_W64);
    float* yyL  = (float*)(smem + L_YY);
    float* resP = (float*)(smem + L_RES);
    float* jacP = (float*)(smem + L_JAC);

    const f16* w1fh = (const f16*)(ws + WS_W1F_HI) + (size_t)d * 8192;
    const f16* w1fl = (const f16*)(ws + WS_W1F_LO) + (size_t)d * 8192;
    const f16* w1tf = (const f16*)(ws + WS_W1TF)   + (size_t)d * 8192;
    const float* w64p = (const float*)(ws + WS_W64);

    // ---------- stage: x tile (f32 global, L2-hot) split to hi/lo f16 in LDS ----------
    {
        const float4* xs = (const float4*)(x + (size_t)(b * 514 + t0) * 32);
        for (int u = tid; u < 528; u += 256) {          // 66 rows x 8 float4
            float4 v = xs[u];
            int row = u >> 3, c4 = u & 7;
            half4 hi, lo;
            #pragma unroll
            for (int j = 0; j < 4; ++j) {
                float vv = (&v.x)[j];
                f16 h = (f16)vv;
                hi[j] = h;
                lo[j] = (f16)((vv - (float)h) * 4096.0f);
            }
            *(half4*)(smem + L_XSHI + (row * XS_ROW + c4 * 4) * 2) = hi;
            *(half4*)(smem + L_XSLO + (row * XS_ROW + c4 * 4) * 2) = lo;
        }
        if (tid < 128) {
            b1L[tid]  = b1[d * 128 + tid];
            W2L[tid]  = W2[d * 128 + tid];
            w64L[tid] = w64p[d * 128 + tid];
        }
        if (tid < 64) yyL[tid] = x[(size_t)(b * 514 + t0 + tid + 2) * 32 + d];
    }
    __syncthreads();

    float yyv[4];
    #pragma unroll
    for (int nt = 0; nt < 4; ++nt) yyv[nt] = yyL[nt * 16 + c];

    float res[4] = {0.f, 0.f, 0.f, 0.f}, j64[4] = {0.f, 0.f, 0.f, 0.f};

    // ---------- phase 1 in two ht-passes: {24 MFMA -> epilogue} each ----------
    #pragma unroll
    for (int ht = 0; ht < 2; ++ht) {
        floatx4 accP[4], accQ[4];
        #pragma unroll
        for (int nt = 0; nt < 4; ++nt) { accP[nt] = (floatx4)0.f; accQ[nt] = (floatx4)0.f; }

        #pragma unroll
        for (int ks = 0; ks < 2; ++ks) {
            const int fo = (((wave * 2 + ht) * 2 + ks) * 64 + lane) * 8;
            const half8 aH = *(const half8*)(w1fh + fo);
            const half8 aL = *(const half8*)(w1fl + fo);
            half8 bH[4], bL[4];
            #pragma unroll
            for (int nt = 0; nt < 4; ++nt) {
                const int off = (nt * 16 + c + ks) * XS_ROW + q * 8;  // window overlap trick
                bH[nt] = *(const half8*)(smem + L_XSHI + off * 2);
                bL[nt] = *(const half8*)(smem + L_XSLO + off * 2);
            }
            #pragma unroll
            for (int nt = 0; nt < 4; ++nt) {
                accP[nt] = __builtin_amdgcn_mfma_f32_16x16x32_f16(aH, bH[nt], accP[nt], 0, 0, 0);
                accQ[nt] = __builtin_amdgcn_mfma_f32_16x16x32_f16(aH, bL[nt], accQ[nt], 0, 0, 0);
                accQ[nt] = __builtin_amdgcn_mfma_f32_16x16x32_f16(aL, bH[nt], accQ[nt], 0, 0, 0);
            }
        }

        // per-ht scalar hoist (short-lived: 16 regs within this pass)
        const int hbase = wave * 32 + ht * 16 + q * 4;   // D row = q*4 + reg
        float b1v[4], W2a[4], W2b[4], w64v[4];
        #pragma unroll
        for (int r = 0; r < 4; ++r) {
            const int h = hbase + r;
            b1v[r]  = b1L[h];
            float w2 = W2L[h];
            W2a[r]  = w2;
            W2b[r]  = 0.01f * w2;
            w64v[r] = w64L[h];
        }

        // epilogue for this ht: pre -> g (LDS, A-layout), res/jac64 partials
        // (GB region disjoint from XS; per-wave h-columns -> no barrier needed)
        #pragma unroll
        for (int nt = 0; nt < 4; ++nt) {
            const int n = nt * 16 + c;                   // D col = lane&15
            half4 gp;
            #pragma unroll
            for (int r = 0; r < 4; ++r) {
                const float pre = accP[nt][r] + accQ[nt][r] * (1.0f / 4096.0f)
                                + b1v[r] + yyv[nt] * w64v[r];
                const float gg = (pre >= 0.f) ? W2a[r] : W2b[r];
                res[nt] += pre * gg;
                j64[nt] += gg * w64v[r];
                gp[r] = (f16)gg;
            }
            *(half4*)(smem + L_GB + (n * GB_HP + hbase) * 2) = gp;
        }
    }

    #pragma unroll
    for (int nt = 0; nt < 4; ++nt) {
        float rv = res[nt];
        rv += __shfl_xor(rv, 16, 64);
        rv += __shfl_xor(rv, 32, 64);
        float jv = j64[nt];
        jv += __shfl_xor(jv, 16, 64);
        jv += __shfl_xor(jv, 32, 64);
        if (lane < 16) {
            resP[wave * 64 + nt * 16 + lane] = rv;
            jacP[wave * 64 + nt * 16 + lane] = jv;
        }
    }
    __syncthreads();

    // ---------- residuals (d-major, coalesced) + logabsdet (one wave) ----------
    if (tid < 64) {
        const int n = tid;
        float r = b2[d], j = 0.f;
        #pragma unroll
        for (int w = 0; w < 4; ++w) { r += resP[w * 64 + n]; j += jacP[w * 64 + n]; }
        resw[(size_t)d * 32768 + (size_t)(b * 512 + t0) + n] = r;
        float lg = logf(fabsf(j));
        #pragma unroll
        for (int off = 32; off > 0; off >>= 1) lg += __shfl_down(lg, off, 64);
        if (tid == 0) atomicAdd(out + OUT1_OFF + b, lg);
    }

    // ---------- phase 2 (kt-ownership, operand-swapped): wave owns k-slice ----------
    // acc2[nt] = sum_ks mfma(wF[ks][kt=wave], gF[ks][nt]):
    //   A = w1tf frag for THIS wave's k-tile only (4 x 1KB loads, no redundancy)
    //   B = g rows nt*16+c from GB (same bank-clean pattern as R5's aF reads)
    // D[m=k=wave*16+q*4+r][n=nt*16+c] -> 4 consecutive k per lane -> direct
    // dwordx4 stores (waves write disjoint k-columns; L2 merges 64B segments).
    floatx4 acc2[4];
    #pragma unroll
    for (int nt = 0; nt < 4; ++nt) acc2[nt] = (floatx4)0.f;
    #pragma unroll
    for (int ks = 0; ks < 4; ++ks) {
        const half8 wF = *(const half8*)(w1tf + ((ks * 4 + wave) * 64 + lane) * 8);
        #pragma unroll
        for (int nt = 0; nt < 4; ++nt) {
            const half8 gF = *(const half8*)(smem + L_GB + ((nt * 16 + c) * GB_HP + ks * 32 + q * 8) * 2);
            acc2[nt] = __builtin_amdgcn_mfma_f32_16x16x32_f16(wF, gF, acc2[nt], 0, 0, 0);
        }
    }
    {
        float* out2 = out + OUT2_OFF + (size_t)d * ((size_t)32768 * 64)
                    + (size_t)(b * 512 + t0) * 64;
        #pragma unroll
        for (int nt = 0; nt < 4; ++nt)
            *(floatx4*)(out2 + (size_t)(nt * 16 + c) * 64 + wave * 16 + q * 4) = acc2[nt];
    }
}

// ---- residuals: (d, bn) d-major ws -> (bn, d) out, fully coalesced both sides ----
__global__ __launch_bounds__(256) void finish_res_kernel(
    const float* __restrict__ resw, float* __restrict__ out)
{
    __shared__ float tile[32][65];
    const int n0 = blockIdx.x * 64;   // 512 blocks
    const int tid = threadIdx.x;
    #pragma unroll
    for (int i = 0; i < 8; ++i) {
        int idx = i * 256 + tid;              // 0..2047
        int dd = idx >> 6, n = idx & 63;
        tile[dd][n] = resw[(size_t)dd * 32768 + n0 + n];
    }
    __syncthreads();
    #pragma unroll
    for (int i = 0; i < 8; ++i) {
        int idx = i * 256 + tid;
        int n = idx >> 5, dd = idx & 31;
        out[(size_t)(n0 + n) * 32 + dd] = tile[dd][n];
    }
}

extern "C" void kernel_launch(void* const* d_in, const int* in_sizes, int n_in,
                              void* d_out, int out_size, void* d_ws, size_t ws_size,
                              hipStream_t stream) {
    const float* x  = (const float*)d_in[0];
    const float* W1 = (const float*)d_in[1];
    const float* b1 = (const float*)d_in[2];
    const float* W2 = (const float*)d_in[3];
    const float* b2 = (const float*)d_in[4];
    float* out = (float*)d_out;
    char* ws = (char*)d_ws;

    hipMemsetAsync(out + OUT1_OFF, 0, 64 * sizeof(float), stream);

    hipLaunchKernelGGL(split_w1_kernel, dim3((32 * 128 * 64 + 255) / 256), dim3(256), 0, stream,
                       W1, (f16*)(ws + WS_W1F_HI), (f16*)(ws + WS_W1F_LO),
                       (f16*)(ws + WS_W1TF), (float*)(ws + WS_W64));

    hipLaunchKernelGGL(np_main_kernel, dim3(512, 32), dim3(256), L_TOTAL, stream,
                       x, b1, W2, b2, (const char*)ws, (float*)(ws + WS_RES), out);

    hipLaunchKernelGGL(finish_res_kernel, dim3(512), dim3(256), 0, stream,
                       (const float*)(ws + WS_RES), out);
}